// Round 1
// baseline (424.988 us; speedup 1.0000x reference)
//
#include <hip/hip_runtime.h>

// One thread per batch column, interpolation search instead of binary search.
//
// times[:,b] are sorted U(0,1) samples, so count(times <= tq) ~
// Binomial(ntime, tq) with sigma = sqrt(ntime*p*(1-p)) <= 16 for ntime=1024.
// The old kernel did 10 *dependent* scattered loads (binary search) + 2 value
// gathers = ~12 serial memory round-trips with 1 wave/SIMD (grid is
// work-limited) -> round-trip-latency bound. Here we spend slightly more
// traffic to get 3 probe rounds of 8/7/4 *independent* loads each:
//   R1: 8 probes stride 32 over guess+/-112 (7 sigma)  -> width-32 bucket
//   R2: 7 probes stride 4                              -> width-4 bucket
//   R3: 4 unit probes                                  -> exact index
// plus the final values[] gather round = 4 dependent rounds total.
// A generic binary-search fallback (while hi-lo > 32) keeps this correct for
// ANY sorted input; on the expected distribution it executes 0 iterations.
//
// Bracket invariant throughout: times[lo-1] <= tq < times[hi] with virtual
// times[-1] = -inf, times[ntime] = +inf; t0v/t1v cache times[lo-1]/times[hi]
// whenever lo>0 / hi<ntime, so the epilogue needs no extra times[] reads.
__global__ void __launch_bounds__(256) bts_interp_kernel(
        const float* __restrict__ times,
        const float* __restrict__ values,
        const float* __restrict__ t,
        float* __restrict__ out,
        int ntime, int nbatch) {
    int b = blockIdx.x * blockDim.x + threadIdx.x;
    if (b >= nbatch) return;

    const long stride = (long)nbatch;
    float tq = t[b];

    int lo = 0, hi = ntime;
    float t0v = 0.0f;  // times[lo-1] once lo > 0
    float t1v = 0.0f;  // times[hi]   once hi < ntime

    if (ntime >= 256) {
        // ---- Round 1: 8 independent probes, stride 32, centered on guess.
        int g = (int)(tq * (float)ntime);   // E[count] = ntime*tq
        int W = g - 112;                    // probes cover [g-112, g+112]
        if (W < 0) W = 0;
        if (W > ntime - 256) W = ntime - 256;
        float pv[8];
#pragma unroll
        for (int i = 0; i < 8; ++i)
            pv[i] = times[(long)(W + 32 * i) * stride + b];
#pragma unroll
        for (int i = 0; i < 8; ++i) {
            int p = W + 32 * i;
            if (pv[i] <= tq) { int nl = p + 1; if (nl > lo) { lo = nl; t0v = pv[i]; } }
            else if (p < hi) { hi = p; t1v = pv[i]; }
        }
    }

    // ---- Fallback: guarantees width <= 32 for any sorted input.
    // On the expected distribution this runs 0 iterations (miss prob ~1e-9).
    while (hi - lo > 32) {
        int mid = (lo + hi) >> 1;
        float v = times[(long)mid * stride + b];
        if (v <= tq) { lo = mid + 1; t0v = v; }
        else         { hi = mid;     t1v = v; }
    }

    {   // ---- Round 2: 7 independent probes, stride 4: width<=32 -> <=4.
        int base = lo;
        int pi[7]; float pv[7];
#pragma unroll
        for (int i = 0; i < 7; ++i) {
            int p = base + 4 * (i + 1);
            if (p > ntime - 1) p = ntime - 1;   // clamped probes stay consistent
            pi[i] = p;
            pv[i] = times[(long)p * stride + b];
        }
#pragma unroll
        for (int i = 0; i < 7; ++i) {
            if (pv[i] <= tq) { int nl = pi[i] + 1; if (nl > lo) { lo = nl; t0v = pv[i]; } }
            else if (pi[i] < hi) { hi = pi[i]; t1v = pv[i]; }
        }
    }

    {   // ---- Round 3: 4 independent unit probes: width<=4 -> exact.
        int base = lo;
        int pi[4]; float pv[4];
#pragma unroll
        for (int i = 0; i < 4; ++i) {
            int p = base + i;
            if (p > ntime - 1) p = ntime - 1;
            pi[i] = p;
            pv[i] = times[(long)p * stride + b];
        }
#pragma unroll
        for (int i = 0; i < 4; ++i) {
            if (pv[i] <= tq) { int nl = pi[i] + 1; if (nl > lo) { lo = nl; t0v = pv[i]; } }
            else if (pi[i] < hi) { hi = pi[i]; t1v = pv[i]; }
        }
    }
    // Now lo == hi == count(times[:,b] <= tq) in [0, ntime], with
    // t0v = times[lo-1] (if lo>0) and t1v = times[lo] (if lo<ntime).

    float res;
    if (lo > 0 && lo < ntime) {
        // normal case: iv = isl = lo-1
        long base2 = (long)(lo - 1) * stride + b;
        float va = values[base2];
        float vb = values[base2 + stride];
        res = va + (vb - va) / (t1v - t0v) * (tq - t0v);
    } else {
        // gi == 0 (t below all knots, or >= all knots): iv = ntime-1, isl = ntime-2
        long base2 = (long)(ntime - 2) * stride + b;
        float ta = times[base2];
        float tb = times[base2 + stride];
        float va = values[base2];
        float vb = values[base2 + stride];
        res = vb + (vb - va) / (tb - ta) * (tq - tb);
    }
    out[b] = res;
}

extern "C" void kernel_launch(void* const* d_in, const int* in_sizes, int n_in,
                              void* d_out, int out_size, void* d_ws, size_t ws_size,
                              hipStream_t stream) {
    const float* times  = (const float*)d_in[0];
    const float* values = (const float*)d_in[1];
    const float* t      = (const float*)d_in[2];
    float* out = (float*)d_out;

    int nbatch = in_sizes[2];
    int ntime  = in_sizes[0] / nbatch;

    const int BLOCK = 256;
    int grid = (nbatch + BLOCK - 1) / BLOCK;
    bts_interp_kernel<<<grid, BLOCK, 0, stream>>>(times, values, t, out, ntime, nbatch);
}